// Round 2
// baseline (457.953 us; speedup 1.0000x reference)
//
#include <hip/hip_runtime.h>
#include <math.h>

// ---------------- workspace layout (float offsets) ----------------
#define NHEAD     10004
#define OFF_HEAD  0        // 10004 head logits
#define OFF_H0    10004    // 512  projected vec, cluster 0
#define OFF_H1    10516    // 256
#define OFF_H2    10772    // 128
#define OFF_H3    10900    // 64
#define OFF_C0    10964    // 10000 cluster-0 logits
#define OFF_C1    20964    // 20000
#define OFF_C2    40964    // 40000
#define OFF_C3    80964    // 20000
#define OFF_ACC   100964   // acc[0]=head esum, acc[1..4]=cluster esums, acc[5]=target lp sum

__device__ __forceinline__ float wave_sum(float v) {
  v += __shfl_xor(v, 32, 64);
  v += __shfl_xor(v, 16, 64);
  v += __shfl_xor(v, 8, 64);
  v += __shfl_xor(v, 4, 64);
  v += __shfl_xor(v, 2, 64);
  v += __shfl_xor(v, 1, 64);
  return v;
}

__global__ __launch_bounds__(64) void init_kernel(float* __restrict__ ws) {
  if (threadIdx.x < 8) ws[OFF_ACC + threadIdx.x] = 0.f;
}

// Kernel 1: dot(row, feature) for 10004 head rows + 960 projection rows.
// Blocks 0..625: head (16 rows). Blocks 626..685: projection rows.
// Wave-per-row x4, all 16 float4 loads staged in registers before reduction.
__global__ __launch_bounds__(256) void head_proj_kernel(
    const float* __restrict__ feat, const float* __restrict__ head_w,
    const float* __restrict__ p0, const float* __restrict__ p1,
    const float* __restrict__ p2, const float* __restrict__ p3,
    float* __restrict__ ws) {
  __shared__ __align__(16) float sf[1024];
  ((float4*)sf)[threadIdx.x] = ((const float4*)feat)[threadIdx.x];
  __syncthreads();
  const float4* sf4 = (const float4*)sf;
  const int wave = threadIdx.x >> 6, lane = threadIdx.x & 63;
  const int b = blockIdx.x;

  if (b < 626) {  // head rows
    const int row0 = b * 16 + wave * 4;
    float4 a[4][4];
#pragma unroll
    for (int k = 0; k < 4; ++k) {
      int row = min(row0 + k, NHEAD - 1);  // clamp so loads stay unconditional
      const float4* src4 = (const float4*)head_w + (size_t)row * 256;
#pragma unroll
      for (int j = 0; j < 4; ++j) a[k][j] = src4[lane + j * 64];
    }
    float esum = 0.f;
#pragma unroll
    for (int k = 0; k < 4; ++k) {
      float acc = 0.f;
#pragma unroll
      for (int j = 0; j < 4; ++j) {
        float4 c = sf4[lane + j * 64];
        acc += a[k][j].x * c.x + a[k][j].y * c.y + a[k][j].z * c.z + a[k][j].w * c.w;
      }
      acc = wave_sum(acc);
      if (lane == 0 && row0 + k < NHEAD) { ws[OFF_HEAD + row0 + k] = acc; esum += expf(acc); }
    }
    if (lane == 0) atomicAdd(&ws[OFF_ACC + 0], esum);
  } else {        // projection rows: ws[row] layout matches (OFF_H0.. contiguous after head)
    const int pb = b - 626;
    const int row0 = NHEAD + pb * 16 + wave * 4;
    float4 a[4][4];
#pragma unroll
    for (int k = 0; k < 4; ++k) {
      int row = row0 + k;  // 10004..10963, always valid
      const float* src;
      if (row < 10516)      src = p0 + (size_t)(row - 10004) * 1024;
      else if (row < 10772) src = p1 + (size_t)(row - 10516) * 1024;
      else if (row < 10900) src = p2 + (size_t)(row - 10772) * 1024;
      else                  src = p3 + (size_t)(row - 10900) * 1024;
      const float4* src4 = (const float4*)src;
#pragma unroll
      for (int j = 0; j < 4; ++j) a[k][j] = src4[lane + j * 64];
    }
#pragma unroll
    for (int k = 0; k < 4; ++k) {
      float acc = 0.f;
#pragma unroll
      for (int j = 0; j < 4; ++j) {
        float4 c = sf4[lane + j * 64];
        acc += a[k][j].x * c.x + a[k][j].y * c.y + a[k][j].z * c.z + a[k][j].w * c.w;
      }
      acc = wave_sum(acc);
      if (lane == 0) ws[row0 + k] = acc;
    }
  }
}

// Kernel 2: cluster logits. Wave-per-row x4, loads staged before reduction.
// Blocks: [0,625) c0(h=512)  [625,1875) c1(h=256)  [1875,4375) c2(h=128)  [4375,5625) c3(h=64)
__global__ __launch_bounds__(256) void tail_kernel(
    const float* __restrict__ w0, const float* __restrict__ w1,
    const float* __restrict__ w2, const float* __restrict__ w3,
    float* __restrict__ ws) {
  __shared__ __align__(16) float sh[512];
  const int b = blockIdx.x;
  const float* w; int h, hoff, coff, ci, lb;
  if (b < 625)       { w = w0; h = 512; hoff = OFF_H0; coff = OFF_C0; ci = 1; lb = b; }
  else if (b < 1875) { w = w1; h = 256; hoff = OFF_H1; coff = OFF_C1; ci = 2; lb = b - 625; }
  else if (b < 4375) { w = w2; h = 128; hoff = OFF_H2; coff = OFF_C2; ci = 3; lb = b - 1875; }
  else               { w = w3; h = 64;  hoff = OFF_H3; coff = OFF_C3; ci = 4; lb = b - 4375; }
  for (int t = threadIdx.x; t < h; t += 256) sh[t] = ws[hoff + t];
  __syncthreads();
  const int wave = threadIdx.x >> 6, lane = threadIdx.x & 63;
  const int row0 = lb * 16 + wave * 4;
  float esum = 0.f;
  if (h == 512) {
    float4 a[4][2];
#pragma unroll
    for (int k = 0; k < 4; ++k) {
      const float4* wr4 = (const float4*)(w + (size_t)(row0 + k) * 512);
#pragma unroll
      for (int j = 0; j < 2; ++j) a[k][j] = wr4[lane + j * 64];
    }
    const float4* sh4 = (const float4*)sh;
#pragma unroll
    for (int k = 0; k < 4; ++k) {
      float acc = 0.f;
#pragma unroll
      for (int j = 0; j < 2; ++j) {
        float4 c = sh4[lane + j * 64];
        acc += a[k][j].x * c.x + a[k][j].y * c.y + a[k][j].z * c.z + a[k][j].w * c.w;
      }
      acc = wave_sum(acc);
      if (lane == 0) { ws[coff + row0 + k] = acc; esum += expf(acc); }
    }
  } else if (h == 256) {
    float4 a[4];
#pragma unroll
    for (int k = 0; k < 4; ++k) a[k] = ((const float4*)(w + (size_t)(row0 + k) * 256))[lane];
    const float4 c = ((const float4*)sh)[lane];
#pragma unroll
    for (int k = 0; k < 4; ++k) {
      float acc = a[k].x * c.x + a[k].y * c.y + a[k].z * c.z + a[k].w * c.w;
      acc = wave_sum(acc);
      if (lane == 0) { ws[coff + row0 + k] = acc; esum += expf(acc); }
    }
  } else if (h == 128) {
    float2 a[4];
#pragma unroll
    for (int k = 0; k < 4; ++k) a[k] = ((const float2*)(w + (size_t)(row0 + k) * 128))[lane];
    const float2 c = ((const float2*)sh)[lane];
#pragma unroll
    for (int k = 0; k < 4; ++k) {
      float acc = a[k].x * c.x + a[k].y * c.y;
      acc = wave_sum(acc);
      if (lane == 0) { ws[coff + row0 + k] = acc; esum += expf(acc); }
    }
  } else {
    float a[4];
#pragma unroll
    for (int k = 0; k < 4; ++k) a[k] = w[(size_t)(row0 + k) * 64 + lane];
    const float c = sh[lane];
#pragma unroll
    for (int k = 0; k < 4; ++k) {
      float acc = wave_sum(a[k] * c);
      if (lane == 0) { ws[coff + row0 + k] = acc; esum += expf(acc); }
    }
  }
  if (lane == 0) atomicAdd(&ws[OFF_ACC + ci], esum);
}

// Kernel 3: 16 blocks x 256 threads, one target each; atomicAdd partial sums.
__global__ __launch_bounds__(256) void gather_kernel(
    const int* __restrict__ targets, float* __restrict__ ws) {
  const float lse0 = logf(ws[OFF_ACC + 0]);
  const float lse1 = logf(ws[OFF_ACC + 1]);
  const float lse2 = logf(ws[OFF_ACC + 2]);
  const float lse3 = logf(ws[OFF_ACC + 3]);
  const float lse4 = logf(ws[OFF_ACC + 4]);
  const int i = blockIdx.x * 256 + threadIdx.x;
  const int t = targets[i];
  float lp;
  if (t < 10000)      lp = ws[OFF_HEAD + t] - lse0;
  else if (t < 20000) lp = ws[OFF_C0 + t - 10000] - lse1 + (ws[10000] - lse0);
  else if (t < 40000) lp = ws[OFF_C1 + t - 20000] - lse2 + (ws[10001] - lse0);
  else if (t < 80000) lp = ws[OFF_C2 + t - 40000] - lse3 + (ws[10002] - lse0);
  else                lp = ws[OFF_C3 + t - 80000] - lse4 + (ws[10003] - lse0);
  float s = wave_sum(lp);
  __shared__ float wred[4];
  const int wave = threadIdx.x >> 6, lane = threadIdx.x & 63;
  if (lane == 0) wred[wave] = s;
  __syncthreads();
  if (threadIdx.x == 0) atomicAdd(&ws[OFF_ACC + 5], wred[0] + wred[1] + wred[2] + wred[3]);
}

__global__ __launch_bounds__(64) void writeout_kernel(
    const float* __restrict__ ws, float* __restrict__ out) {
  if (threadIdx.x == 0) out[0] = -ws[OFF_ACC + 5] * (1.f / 4096.f);
}

extern "C" void kernel_launch(void* const* d_in, const int* in_sizes, int n_in,
                              void* d_out, int out_size, void* d_ws, size_t ws_size,
                              hipStream_t stream) {
  const float* feat    = (const float*)d_in[0];
  const int*   targets = (const int*)d_in[1];
  const float* head_w  = (const float*)d_in[2];
  const float* t0p = (const float*)d_in[3];
  const float* t0w = (const float*)d_in[4];
  const float* t1p = (const float*)d_in[5];
  const float* t1w = (const float*)d_in[6];
  const float* t2p = (const float*)d_in[7];
  const float* t2w = (const float*)d_in[8];
  const float* t3p = (const float*)d_in[9];
  const float* t3w = (const float*)d_in[10];
  float* ws  = (float*)d_ws;
  float* out = (float*)d_out;

  init_kernel<<<1, 64, 0, stream>>>(ws);
  head_proj_kernel<<<686, 256, 0, stream>>>(feat, head_w, t0p, t1p, t2p, t3p, ws);
  tail_kernel<<<5625, 256, 0, stream>>>(t0w, t1w, t2w, t3w, ws);
  gather_kernel<<<16, 256, 0, stream>>>(targets, ws);
  writeout_kernel<<<1, 64, 0, stream>>>(ws, out);
}

// Round 3
// 170.446 us; speedup vs baseline: 2.6868x; 2.6868x over previous
//
#include <hip/hip_runtime.h>
#include <math.h>

// ---------------- workspace layout (float offsets) ----------------
#define NHEAD     10004
#define OFF_HEAD  0        // 10004 head logits
#define OFF_H0    10004    // 512  projected vec, cluster 0
#define OFF_H1    10516    // 256
#define OFF_H2    10772    // 128
#define OFF_H3    10900    // 64
#define OFF_C0    10964    // 10000 cluster-0 logits
#define OFF_C1    20964    // 20000
#define OFF_C2    40964    // 40000
#define OFF_C3    80964    // 20000
#define OFF_PH    100964   // 626 per-block partial sum(exp), head
#define OFF_P0    101590   // 625 cluster 0
#define OFF_P1    102215   // 625 cluster 1
#define OFF_P2    102840   // 1250 cluster 2
#define OFF_P3    104090   // 313 cluster 3
#define OFF_G     104403   // 16 per-block gathered-logprob sums

__device__ __forceinline__ float wave_sum(float v) {
  v += __shfl_xor(v, 32, 64);
  v += __shfl_xor(v, 16, 64);
  v += __shfl_xor(v, 8, 64);
  v += __shfl_xor(v, 4, 64);
  v += __shfl_xor(v, 2, 64);
  v += __shfl_xor(v, 1, 64);
  return v;
}

// Kernel 1: dot(row, feature) for 10004 head rows + 960 projection rows.
// Blocks 0..625: head (16 rows each). Blocks 626..685: projection rows.
__global__ __launch_bounds__(256) void head_proj_kernel(
    const float* __restrict__ feat, const float* __restrict__ head_w,
    const float* __restrict__ p0, const float* __restrict__ p1,
    const float* __restrict__ p2, const float* __restrict__ p3,
    float* __restrict__ ws) {
  __shared__ __align__(16) float sf[1024];
  ((float4*)sf)[threadIdx.x] = ((const float4*)feat)[threadIdx.x];
  __syncthreads();
  const float4* sf4 = (const float4*)sf;
  const int wave = threadIdx.x >> 6, lane = threadIdx.x & 63;
  const int b = blockIdx.x;

  if (b < 626) {  // head rows, partial sum(exp) per block
    float esum = 0.f;
#pragma unroll
    for (int k = 0; k < 4; ++k) {
      int row = b * 16 + wave * 4 + k;
      if (row < NHEAD) {
        const float4* src4 = (const float4*)head_w + (size_t)row * 256;
        float acc = 0.f;
#pragma unroll
        for (int j = 0; j < 4; ++j) {
          float4 a = src4[lane + j * 64];
          float4 c = sf4[lane + j * 64];
          acc += a.x * c.x + a.y * c.y + a.z * c.z + a.w * c.w;
        }
        acc = wave_sum(acc);
        if (lane == 0) { ws[OFF_HEAD + row] = acc; esum += expf(acc); }
      }
    }
    __shared__ float wred[4];
    if (lane == 0) wred[wave] = esum;
    __syncthreads();
    if (threadIdx.x == 0) ws[OFF_PH + b] = wred[0] + wred[1] + wred[2] + wred[3];
  } else {        // projection rows: ws[row] layout matches head-adjacent region
    const int pb = b - 626;
#pragma unroll
    for (int k = 0; k < 4; ++k) {
      int row = NHEAD + pb * 16 + wave * 4 + k;  // 10004..10963
      const float* src;
      if (row < 10516)      src = p0 + (size_t)(row - 10004) * 1024;
      else if (row < 10772) src = p1 + (size_t)(row - 10516) * 1024;
      else if (row < 10900) src = p2 + (size_t)(row - 10772) * 1024;
      else                  src = p3 + (size_t)(row - 10900) * 1024;
      const float4* src4 = (const float4*)src;
      float acc = 0.f;
#pragma unroll
      for (int j = 0; j < 4; ++j) {
        float4 a = src4[lane + j * 64];
        float4 c = sf4[lane + j * 64];
        acc += a.x * c.x + a.y * c.y + a.z * c.z + a.w * c.w;
      }
      acc = wave_sum(acc);
      if (lane == 0) ws[row] = acc;
    }
  }
}

// Kernel 2: cluster logits, wave-per-row, partial sum(exp) per block.
// Blocks: [0,625) c0 h=512 16rows/blk | [625,1250) c1 h=256 32rows/blk
//         [1250,2500) c2 h=128 32rows/blk | [2500,2813) c3 h=64 64rows/blk
__global__ __launch_bounds__(256) void tail_kernel(
    const float* __restrict__ w0, const float* __restrict__ w1,
    const float* __restrict__ w2, const float* __restrict__ w3,
    float* __restrict__ ws) {
  __shared__ __align__(16) float sh[512];
  __shared__ float wred[4];
  const int b = blockIdx.x;
  const int wave = threadIdx.x >> 6, lane = threadIdx.x & 63;
  float esum = 0.f;
  int poff, lb;

  if (b < 625) {            // c0: h=512, 4 rows/wave
    lb = b; poff = OFF_P0;
    for (int t = threadIdx.x; t < 512; t += 256) sh[t] = ws[OFF_H0 + t];
    __syncthreads();
    const float4* sh4 = (const float4*)sh;
    const int row0 = lb * 16 + wave * 4;
#pragma unroll
    for (int k = 0; k < 4; ++k) {
      const float4* wr4 = (const float4*)(w0 + (size_t)(row0 + k) * 512);
      float acc = 0.f;
#pragma unroll
      for (int j = 0; j < 2; ++j) {
        float4 a = wr4[lane + j * 64]; float4 c = sh4[lane + j * 64];
        acc += a.x * c.x + a.y * c.y + a.z * c.z + a.w * c.w;
      }
      acc = wave_sum(acc);
      if (lane == 0) { ws[OFF_C0 + row0 + k] = acc; esum += expf(acc); }
    }
  } else if (b < 1250) {    // c1: h=256, 8 rows/wave
    lb = b - 625; poff = OFF_P1;
    if (threadIdx.x < 256) sh[threadIdx.x] = ws[OFF_H1 + threadIdx.x];
    __syncthreads();
    const float4 c = ((const float4*)sh)[lane];
    const int row0 = lb * 32 + wave * 8;
#pragma unroll
    for (int k = 0; k < 8; ++k) {
      float4 a = ((const float4*)(w1 + (size_t)(row0 + k) * 256))[lane];
      float acc = a.x * c.x + a.y * c.y + a.z * c.z + a.w * c.w;
      acc = wave_sum(acc);
      if (lane == 0) { ws[OFF_C1 + row0 + k] = acc; esum += expf(acc); }
    }
  } else if (b < 2500) {    // c2: h=128, 8 rows/wave
    lb = b - 1250; poff = OFF_P2;
    if (threadIdx.x < 128) sh[threadIdx.x] = ws[OFF_H2 + threadIdx.x];
    __syncthreads();
    const float2 c = ((const float2*)sh)[lane];
    const int row0 = lb * 32 + wave * 8;
#pragma unroll
    for (int k = 0; k < 8; ++k) {
      float2 a = ((const float2*)(w2 + (size_t)(row0 + k) * 128))[lane];
      float acc = a.x * c.x + a.y * c.y;
      acc = wave_sum(acc);
      if (lane == 0) { ws[OFF_C2 + row0 + k] = acc; esum += expf(acc); }
    }
  } else {                  // c3: h=64, 16 rows/wave (last block partial)
    lb = b - 2500; poff = OFF_P3;
    if (threadIdx.x < 64) sh[threadIdx.x] = ws[OFF_H3 + threadIdx.x];
    __syncthreads();
    const float c = sh[lane];
    const int row0 = lb * 64 + wave * 16;
#pragma unroll
    for (int k = 0; k < 16; ++k) {
      int row = row0 + k;
      int rc = min(row, 19999);
      float a = w3[(size_t)rc * 64 + lane];
      float acc = wave_sum(a * c);
      if (lane == 0 && row < 20000) { ws[OFF_C3 + row] = acc; esum += expf(acc); }
    }
  }
  if (lane == 0) wred[wave] = esum;
  __syncthreads();
  if (threadIdx.x == 0) ws[poff + lb] = wred[0] + wred[1] + wred[2] + wred[3];
}

// Kernel 3: 16 blocks. Each block redundantly reduces the partial exp-sum
// arrays (L2-hot, ~13.8 KB) to get the 5 LSEs, gathers 256 targets, writes
// one per-block logprob sum.
__global__ __launch_bounds__(256) void gather_kernel(
    const int* __restrict__ targets, float* __restrict__ ws) {
  __shared__ float red[256];
  __shared__ float slse[5];
  const int offs[5] = {OFF_PH, OFF_P0, OFF_P1, OFF_P2, OFF_P3};
  const int lens[5] = {626, 625, 625, 1250, 313};
  for (int s = 0; s < 5; ++s) {
    float v = 0.f;
    for (int i = threadIdx.x; i < lens[s]; i += 256) v += ws[offs[s] + i];
    red[threadIdx.x] = v; __syncthreads();
    for (int st = 128; st; st >>= 1) {
      if (threadIdx.x < st) red[threadIdx.x] += red[threadIdx.x + st];
      __syncthreads();
    }
    if (threadIdx.x == 0) slse[s] = logf(red[0]);
    __syncthreads();
  }
  const float lse0 = slse[0], lse1 = slse[1], lse2 = slse[2], lse3 = slse[3], lse4 = slse[4];
  const int i = blockIdx.x * 256 + threadIdx.x;
  const int t = targets[i];
  float lp;
  if (t < 10000)      lp = ws[OFF_HEAD + t] - lse0;
  else if (t < 20000) lp = ws[OFF_C0 + t - 10000] - lse1 + (ws[10000] - lse0);
  else if (t < 40000) lp = ws[OFF_C1 + t - 20000] - lse2 + (ws[10001] - lse0);
  else if (t < 80000) lp = ws[OFF_C2 + t - 40000] - lse3 + (ws[10002] - lse0);
  else                lp = ws[OFF_C3 + t - 80000] - lse4 + (ws[10003] - lse0);
  float s = wave_sum(lp);
  __shared__ float wred[4];
  const int wave = threadIdx.x >> 6, lane = threadIdx.x & 63;
  if (lane == 0) wred[wave] = s;
  __syncthreads();
  if (threadIdx.x == 0) ws[OFF_G + blockIdx.x] = wred[0] + wred[1] + wred[2] + wred[3];
}

__global__ __launch_bounds__(64) void writeout_kernel(
    const float* __restrict__ ws, float* __restrict__ out) {
  float v = (threadIdx.x < 16) ? ws[OFF_G + threadIdx.x] : 0.f;
  v = wave_sum(v);
  if (threadIdx.x == 0) out[0] = -v * (1.f / 4096.f);
}

extern "C" void kernel_launch(void* const* d_in, const int* in_sizes, int n_in,
                              void* d_out, int out_size, void* d_ws, size_t ws_size,
                              hipStream_t stream) {
  const float* feat    = (const float*)d_in[0];
  const int*   targets = (const int*)d_in[1];
  const float* head_w  = (const float*)d_in[2];
  const float* t0p = (const float*)d_in[3];
  const float* t0w = (const float*)d_in[4];
  const float* t1p = (const float*)d_in[5];
  const float* t1w = (const float*)d_in[6];
  const float* t2p = (const float*)d_in[7];
  const float* t2w = (const float*)d_in[8];
  const float* t3p = (const float*)d_in[9];
  const float* t3w = (const float*)d_in[10];
  float* ws  = (float*)d_ws;
  float* out = (float*)d_out;

  head_proj_kernel<<<686, 256, 0, stream>>>(feat, head_w, t0p, t1p, t2p, t3p, ws);
  tail_kernel<<<2813, 256, 0, stream>>>(t0w, t1w, t2w, t3w, ws);
  gather_kernel<<<16, 256, 0, stream>>>(targets, ws);
  writeout_kernel<<<1, 64, 0, stream>>>(ws, out);
}

// Round 4
// 164.623 us; speedup vs baseline: 2.7818x; 1.0354x over previous
//
#include <hip/hip_runtime.h>
#include <math.h>

// ---------------- workspace layout (float offsets) ----------------
#define NHEAD     10004
#define OFF_HEAD  0        // 10004 head logits
#define OFF_H0    10004    // 512  projected vec, cluster 0
#define OFF_H1    10516    // 256
#define OFF_H2    10772    // 128
#define OFF_H3    10900    // 64
#define OFF_C0    10964    // 10000 cluster-0 logits
#define OFF_C1    20964    // 20000
#define OFF_C2    40964    // 40000
#define OFF_C3    80964    // 20000
// partial exp-sums, contiguous: head 626 | c0 313 | c1 313 | c2 625 | c3 313
#define OFF_P     100964
#define OFF_PH    100964
#define OFF_P0    101590
#define OFF_P1    101903
#define OFF_P2    102216
#define OFF_P3    102841
#define NPART     2190

__device__ __forceinline__ float wave_sum(float v) {
  v += __shfl_xor(v, 32, 64);
  v += __shfl_xor(v, 16, 64);
  v += __shfl_xor(v, 8, 64);
  v += __shfl_xor(v, 4, 64);
  v += __shfl_xor(v, 2, 64);
  v += __shfl_xor(v, 1, 64);
  return v;
}

__device__ __forceinline__ float dot4(float4 a, float4 c) {
  return a.x * c.x + a.y * c.y + a.z * c.z + a.w * c.w;
}

// Kernel 1: dot(row, feature) for 10004 head rows + 960 projection rows.
// Blocks 0..625: head (16 rows each). Blocks 626..685: projection rows.
__global__ __launch_bounds__(256) void head_proj_kernel(
    const float* __restrict__ feat, const float* __restrict__ head_w,
    const float* __restrict__ p0, const float* __restrict__ p1,
    const float* __restrict__ p2, const float* __restrict__ p3,
    float* __restrict__ ws) {
  __shared__ __align__(16) float sf[1024];
  ((float4*)sf)[threadIdx.x] = ((const float4*)feat)[threadIdx.x];
  __syncthreads();
  const float4* sf4 = (const float4*)sf;
  const int wave = threadIdx.x >> 6, lane = threadIdx.x & 63;
  const int b = blockIdx.x;

  if (b < 626) {  // head rows, partial sum(exp) per block
    float esum = 0.f;
#pragma unroll
    for (int k = 0; k < 4; ++k) {
      int row = b * 16 + wave * 4 + k;
      int rc = min(row, NHEAD - 1);
      const float4* src4 = (const float4*)head_w + (size_t)rc * 256;
      float acc = 0.f;
#pragma unroll
      for (int j = 0; j < 4; ++j) acc += dot4(src4[lane + j * 64], sf4[lane + j * 64]);
      acc = wave_sum(acc);
      if (lane == 0 && row < NHEAD) { ws[OFF_HEAD + row] = acc; esum += expf(acc); }
    }
    __shared__ float wred[4];
    if (lane == 0) wred[wave] = esum;
    __syncthreads();
    if (threadIdx.x == 0) ws[OFF_PH + b] = wred[0] + wred[1] + wred[2] + wred[3];
  } else {        // projection rows: ws[row] layout matches head-adjacent region
    const int pb = b - 626;
#pragma unroll
    for (int k = 0; k < 4; ++k) {
      int row = NHEAD + pb * 16 + wave * 4 + k;  // 10004..10963
      const float* src;
      if (row < 10516)      src = p0 + (size_t)(row - 10004) * 1024;
      else if (row < 10772) src = p1 + (size_t)(row - 10516) * 1024;
      else if (row < 10900) src = p2 + (size_t)(row - 10772) * 1024;
      else                  src = p3 + (size_t)(row - 10900) * 1024;
      const float4* src4 = (const float4*)src;
      float acc = 0.f;
#pragma unroll
      for (int j = 0; j < 4; ++j) acc += dot4(src4[lane + j * 64], sf4[lane + j * 64]);
      acc = wave_sum(acc);
      if (lane == 0) ws[row] = acc;
    }
  }
}

// Kernel 2: cluster logits. All loads float4 (16 B/lane). Per-lane esum, one
// wave reduction at block end.
// Blocks: [0,313) c0 h=512 32r/blk | [313,626) c1 h=256 64r/blk
//         [626,1251) c2 h=128 64r/blk (2 rows per wave-load)
//         [1251,1564) c3 h=64 64r/blk (4 rows per wave-load)
__global__ __launch_bounds__(256) void tail_kernel(
    const float* __restrict__ w0, const float* __restrict__ w1,
    const float* __restrict__ w2, const float* __restrict__ w3,
    float* __restrict__ ws) {
  __shared__ __align__(16) float sh[512];
  __shared__ float wred[4];
  const int b = blockIdx.x;
  const int wave = threadIdx.x >> 6, lane = threadIdx.x & 63;
  float esum = 0.f;
  int poff, lb;

  if (b < 313) {            // c0: h=512, 8 rows/wave
    lb = b; poff = OFF_P0;
    if (threadIdx.x < 128) ((float4*)sh)[threadIdx.x] = ((const float4*)(ws + OFF_H0))[threadIdx.x];
    __syncthreads();
    const float4* sh4 = (const float4*)sh;
    const float4 cv0 = sh4[lane], cv1 = sh4[lane + 64];
    const int row0 = lb * 32 + wave * 8;
#pragma unroll
    for (int k = 0; k < 8; ++k) {
      int rc = min(row0 + k, 9999);
      const float4* wr4 = (const float4*)(w0 + (size_t)rc * 512);
      float acc = dot4(wr4[lane], cv0) + dot4(wr4[lane + 64], cv1);
      acc = wave_sum(acc);
      if (lane == 0 && row0 + k < 10000) { ws[OFF_C0 + row0 + k] = acc; esum += expf(acc); }
    }
  } else if (b < 626) {     // c1: h=256, 16 rows/wave
    lb = b - 313; poff = OFF_P1;
    if (threadIdx.x < 64) ((float4*)sh)[threadIdx.x] = ((const float4*)(ws + OFF_H1))[threadIdx.x];
    __syncthreads();
    const float4 cv = ((const float4*)sh)[lane];
    const int row0 = lb * 64 + wave * 16;
#pragma unroll
    for (int k = 0; k < 16; ++k) {
      int rc = min(row0 + k, 19999);
      float acc = dot4(((const float4*)(w1 + (size_t)rc * 256))[lane], cv);
      acc = wave_sum(acc);
      if (lane == 0 && row0 + k < 20000) { ws[OFF_C1 + row0 + k] = acc; esum += expf(acc); }
    }
  } else if (b < 1251) {    // c2: h=128, one float4 wave-load covers 2 rows
    lb = b - 626; poff = OFF_P2;
    if (threadIdx.x < 32) ((float4*)sh)[threadIdx.x] = ((const float4*)(ws + OFF_H2))[threadIdx.x];
    __syncthreads();
    const float4 cv = ((const float4*)sh)[lane & 31];
    const int row0 = lb * 64 + wave * 16;  // 625 blocks exact, no clamp needed
#pragma unroll
    for (int p = 0; p < 8; ++p) {
      int rbase = row0 + 2 * p;
      // float4 index: rbase*32 + lane -> lanes 0-31 row rbase, 32-63 row rbase+1
      float acc = dot4(((const float4*)w2)[(size_t)rbase * 32 + lane], cv);
      acc += __shfl_xor(acc, 1, 64);
      acc += __shfl_xor(acc, 2, 64);
      acc += __shfl_xor(acc, 4, 64);
      acc += __shfl_xor(acc, 8, 64);
      acc += __shfl_xor(acc, 16, 64);   // each 32-half now holds its row sum
      if ((lane & 31) == 0) {
        int r = rbase + (lane >> 5);
        ws[OFF_C2 + r] = acc; esum += expf(acc);
      }
    }
  } else {                  // c3: h=64, one float4 wave-load covers 4 rows
    lb = b - 1251; poff = OFF_P3;
    if (threadIdx.x < 16) ((float4*)sh)[threadIdx.x] = ((const float4*)(ws + OFF_H3))[threadIdx.x];
    __syncthreads();
    const float4 cv = ((const float4*)sh)[lane & 15];
    const int row0 = lb * 64 + wave * 16;
#pragma unroll
    for (int q = 0; q < 4; ++q) {
      int rb = row0 + 4 * q;
      int rbc = min(rb, 19996);          // quad-aligned clamp (validity is quad-uniform)
      // float4 index: rbc*16 + lane -> 16-lane groups hold rows rbc..rbc+3
      float acc = dot4(((const float4*)w3)[(size_t)rbc * 16 + lane], cv);
      acc += __shfl_xor(acc, 1, 64);
      acc += __shfl_xor(acc, 2, 64);
      acc += __shfl_xor(acc, 4, 64);
      acc += __shfl_xor(acc, 8, 64);     // each 16-group holds its row sum
      if ((lane & 15) == 0 && rb < 20000) {
        int r = rb + (lane >> 4);
        ws[OFF_C3 + r] = acc; esum += expf(acc);
      }
    }
  }
  esum = wave_sum(esum);
  if (lane == 0) wred[wave] = esum;
  __syncthreads();
  if (threadIdx.x == 0) ws[poff + lb] = wred[0] + wred[1] + wred[2] + wred[3];
}

// Kernel 3: single 1024-thread block. One-pass 5-accumulator reduction of the
// contiguous partial array, 5 LSEs, gather 4096 targets (4/thread), mean.
__global__ __launch_bounds__(1024) void finalize_kernel(
    const int* __restrict__ targets, float* __restrict__ ws,
    float* __restrict__ out) {
  const int wv = threadIdx.x >> 6, lane = threadIdx.x & 63;
  float a0 = 0.f, a1 = 0.f, a2 = 0.f, a3 = 0.f, a4 = 0.f;
#pragma unroll
  for (int it = 0; it < 3; ++it) {
    int i = threadIdx.x + it * 1024;
    if (i < NPART) {
      float v = ws[OFF_P + i];
      if (i < 626)       a0 += v;
      else if (i < 939)  a1 += v;
      else if (i < 1252) a2 += v;
      else if (i < 1877) a3 += v;
      else               a4 += v;
    }
  }
  a0 = wave_sum(a0); a1 = wave_sum(a1); a2 = wave_sum(a2);
  a3 = wave_sum(a3); a4 = wave_sum(a4);
  __shared__ float r5[16][5];
  __shared__ float slse[5];
  if (lane == 0) { r5[wv][0] = a0; r5[wv][1] = a1; r5[wv][2] = a2; r5[wv][3] = a3; r5[wv][4] = a4; }
  __syncthreads();
  if (threadIdx.x < 5) {
    float s = 0.f;
#pragma unroll
    for (int w = 0; w < 16; ++w) s += r5[w][threadIdx.x];
    slse[threadIdx.x] = logf(s);
  }
  __syncthreads();
  const float lse0 = slse[0], lse1 = slse[1], lse2 = slse[2], lse3 = slse[3], lse4 = slse[4];
  const float g0 = ws[10000] - lse0, g1 = ws[10001] - lse0;
  const float g2 = ws[10002] - lse0, g3 = ws[10003] - lse0;
  float s = 0.f;
#pragma unroll
  for (int it = 0; it < 4; ++it) {
    int t = targets[threadIdx.x + it * 1024];
    float lp;
    if (t < 10000)      lp = ws[OFF_HEAD + t] - lse0;
    else if (t < 20000) lp = ws[OFF_C0 + t - 10000] - lse1 + g0;
    else if (t < 40000) lp = ws[OFF_C1 + t - 20000] - lse2 + g1;
    else if (t < 80000) lp = ws[OFF_C2 + t - 40000] - lse3 + g2;
    else                lp = ws[OFF_C3 + t - 80000] - lse4 + g3;
    s += lp;
  }
  s = wave_sum(s);
  if (lane == 0) r5[wv][0] = s;
  __syncthreads();
  if (threadIdx.x == 0) {
    float tot = 0.f;
#pragma unroll
    for (int w = 0; w < 16; ++w) tot += r5[w][0];
    out[0] = -tot * (1.f / 4096.f);
  }
}

extern "C" void kernel_launch(void* const* d_in, const int* in_sizes, int n_in,
                              void* d_out, int out_size, void* d_ws, size_t ws_size,
                              hipStream_t stream) {
  const float* feat    = (const float*)d_in[0];
  const int*   targets = (const int*)d_in[1];
  const float* head_w  = (const float*)d_in[2];
  const float* t0p = (const float*)d_in[3];
  const float* t0w = (const float*)d_in[4];
  const float* t1p = (const float*)d_in[5];
  const float* t1w = (const float*)d_in[6];
  const float* t2p = (const float*)d_in[7];
  const float* t2w = (const float*)d_in[8];
  const float* t3p = (const float*)d_in[9];
  const float* t3w = (const float*)d_in[10];
  float* ws  = (float*)d_ws;
  float* out = (float*)d_out;

  head_proj_kernel<<<686, 256, 0, stream>>>(feat, head_w, t0p, t1p, t2p, t3p, ws);
  tail_kernel<<<1564, 256, 0, stream>>>(t0w, t1w, t2w, t3w, ws);
  finalize_kernel<<<1, 1024, 0, stream>>>(targets, ws, out);
}

// Round 5
// 164.518 us; speedup vs baseline: 2.7836x; 1.0006x over previous
//
#include <hip/hip_runtime.h>
#include <math.h>

// ---------------- workspace layout (float offsets) ----------------
#define NHEAD     10004
#define OFF_HEAD  0        // 10004 head logits
#define OFF_H0    10004    // 512  projected vec, cluster 0
#define OFF_H1    10516    // 256
#define OFF_H2    10772    // 128
#define OFF_H3    10900    // 64
#define OFF_C0    10964    // 10000 cluster-0 logits
#define OFF_C1    20964    // 20000
#define OFF_C2    40964    // 40000
#define OFF_C3    80964    // 20000
// partial exp-sums, contiguous: head 313 | c0 313 | c1 313 | c2 625 | c3 313
#define OFF_P     100964
#define OFF_PH    100964
#define OFF_P0    101277
#define OFF_P1    101590
#define OFF_P2    101903
#define OFF_P3    102528
#define NPART     1877

__device__ __forceinline__ float wave_sum(float v) {
  v += __shfl_xor(v, 32, 64);
  v += __shfl_xor(v, 16, 64);
  v += __shfl_xor(v, 8, 64);
  v += __shfl_xor(v, 4, 64);
  v += __shfl_xor(v, 2, 64);
  v += __shfl_xor(v, 1, 64);
  return v;
}

__device__ __forceinline__ float dot4(float4 a, float4 c) {
  return a.x * c.x + a.y * c.y + a.z * c.z + a.w * c.w;
}

// Kernel A: the 960 projection rows only (4 MB — fast, unblocks tail).
__global__ __launch_bounds__(256) void proj_kernel(
    const float* __restrict__ feat,
    const float* __restrict__ p0, const float* __restrict__ p1,
    const float* __restrict__ p2, const float* __restrict__ p3,
    float* __restrict__ ws) {
  __shared__ __align__(16) float sf[1024];
  ((float4*)sf)[threadIdx.x] = ((const float4*)feat)[threadIdx.x];
  __syncthreads();
  const float4* sf4 = (const float4*)sf;
  const int wave = threadIdx.x >> 6, lane = threadIdx.x & 63;
  const int pb = blockIdx.x;
#pragma unroll
  for (int k = 0; k < 4; ++k) {
    int row = NHEAD + pb * 16 + wave * 4 + k;  // 10004..10963
    const float* src;
    if (row < 10516)      src = p0 + (size_t)(row - 10004) * 1024;
    else if (row < 10772) src = p1 + (size_t)(row - 10516) * 1024;
    else if (row < 10900) src = p2 + (size_t)(row - 10772) * 1024;
    else                  src = p3 + (size_t)(row - 10900) * 1024;
    const float4* src4 = (const float4*)src;
    float acc = 0.f;
#pragma unroll
    for (int j = 0; j < 4; ++j) acc += dot4(src4[lane + j * 64], sf4[lane + j * 64]);
    acc = wave_sum(acc);
    if (lane == 0) ws[row] = acc;
  }
}

// Kernel B: head rows + all cluster rows, one launch (107 MB streamed).
// Blocks: [0,313) head 32r/blk | [313,626) c0 h=512 32r/blk
//         [626,939) c1 h=256 64r/blk | [939,1564) c2 h=128 64r/blk
//         [1564,1877) c3 h=64 64r/blk
__global__ __launch_bounds__(256) void main_kernel(
    const float* __restrict__ feat, const float* __restrict__ head_w,
    const float* __restrict__ w0, const float* __restrict__ w1,
    const float* __restrict__ w2, const float* __restrict__ w3,
    float* __restrict__ ws) {
  __shared__ __align__(16) float sh[1024];
  __shared__ float wred[4];
  const int b = blockIdx.x;
  const int wave = threadIdx.x >> 6, lane = threadIdx.x & 63;
  float esum = 0.f;
  int poff, lb;

  if (b < 313) {            // head: 8 rows/wave, D=1024
    lb = b; poff = OFF_PH;
    ((float4*)sh)[threadIdx.x] = ((const float4*)feat)[threadIdx.x];
    __syncthreads();
    const float4* sf4 = (const float4*)sh;
    const int row0 = lb * 32 + wave * 8;
#pragma unroll
    for (int k = 0; k < 8; ++k) {
      int row = row0 + k;
      int rc = min(row, NHEAD - 1);
      const float4* src4 = (const float4*)head_w + (size_t)rc * 256;
      float acc = 0.f;
#pragma unroll
      for (int j = 0; j < 4; ++j) acc += dot4(src4[lane + j * 64], sf4[lane + j * 64]);
      acc = wave_sum(acc);
      if (lane == 0 && row < NHEAD) { ws[OFF_HEAD + row] = acc; esum += expf(acc); }
    }
  } else if (b < 626) {     // c0: h=512, 8 rows/wave
    lb = b - 313; poff = OFF_P0;
    if (threadIdx.x < 128) ((float4*)sh)[threadIdx.x] = ((const float4*)(ws + OFF_H0))[threadIdx.x];
    __syncthreads();
    const float4* sh4 = (const float4*)sh;
    const float4 cv0 = sh4[lane], cv1 = sh4[lane + 64];
    const int row0 = lb * 32 + wave * 8;
#pragma unroll
    for (int k = 0; k < 8; ++k) {
      int rc = min(row0 + k, 9999);
      const float4* wr4 = (const float4*)(w0 + (size_t)rc * 512);
      float acc = dot4(wr4[lane], cv0) + dot4(wr4[lane + 64], cv1);
      acc = wave_sum(acc);
      if (lane == 0 && row0 + k < 10000) { ws[OFF_C0 + row0 + k] = acc; esum += expf(acc); }
    }
  } else if (b < 939) {     // c1: h=256, 16 rows/wave
    lb = b - 626; poff = OFF_P1;
    if (threadIdx.x < 64) ((float4*)sh)[threadIdx.x] = ((const float4*)(ws + OFF_H1))[threadIdx.x];
    __syncthreads();
    const float4 cv = ((const float4*)sh)[lane];
    const int row0 = lb * 64 + wave * 16;
#pragma unroll
    for (int k = 0; k < 16; ++k) {
      int rc = min(row0 + k, 19999);
      float acc = dot4(((const float4*)(w1 + (size_t)rc * 256))[lane], cv);
      acc = wave_sum(acc);
      if (lane == 0 && row0 + k < 20000) { ws[OFF_C1 + row0 + k] = acc; esum += expf(acc); }
    }
  } else if (b < 1564) {    // c2: h=128, one float4 wave-load covers 2 rows
    lb = b - 939; poff = OFF_P2;
    if (threadIdx.x < 32) ((float4*)sh)[threadIdx.x] = ((const float4*)(ws + OFF_H2))[threadIdx.x];
    __syncthreads();
    const float4 cv = ((const float4*)sh)[lane & 31];
    const int row0 = lb * 64 + wave * 16;  // 625 blocks exact
#pragma unroll
    for (int p = 0; p < 8; ++p) {
      int rbase = row0 + 2 * p;
      float acc = dot4(((const float4*)w2)[(size_t)rbase * 32 + lane], cv);
      acc += __shfl_xor(acc, 1, 64);
      acc += __shfl_xor(acc, 2, 64);
      acc += __shfl_xor(acc, 4, 64);
      acc += __shfl_xor(acc, 8, 64);
      acc += __shfl_xor(acc, 16, 64);   // each 32-half holds its row sum
      if ((lane & 31) == 0) {
        int r = rbase + (lane >> 5);
        ws[OFF_C2 + r] = acc; esum += expf(acc);
      }
    }
  } else {                  // c3: h=64, one float4 wave-load covers 4 rows
    lb = b - 1564; poff = OFF_P3;
    if (threadIdx.x < 16) ((float4*)sh)[threadIdx.x] = ((const float4*)(ws + OFF_H3))[threadIdx.x];
    __syncthreads();
    const float4 cv = ((const float4*)sh)[lane & 15];
    const int row0 = lb * 64 + wave * 16;
#pragma unroll
    for (int q = 0; q < 4; ++q) {
      int rb = row0 + 4 * q;
      int rbc = min(rb, 19996);          // quad-aligned clamp
      float acc = dot4(((const float4*)w3)[(size_t)rbc * 16 + lane], cv);
      acc += __shfl_xor(acc, 1, 64);
      acc += __shfl_xor(acc, 2, 64);
      acc += __shfl_xor(acc, 4, 64);
      acc += __shfl_xor(acc, 8, 64);     // each 16-group holds its row sum
      if ((lane & 15) == 0 && rb < 20000) {
        int r = rb + (lane >> 4);
        ws[OFF_C3 + r] = acc; esum += expf(acc);
      }
    }
  }
  esum = wave_sum(esum);
  if (lane == 0) wred[wave] = esum;
  __syncthreads();
  if (threadIdx.x == 0) ws[poff + lb] = wred[0] + wred[1] + wred[2] + wred[3];
}

// Kernel C: single 1024-thread block. One-pass 5-accumulator reduction of the
// contiguous partial array, 5 LSEs, gather 4096 targets (4/thread), mean.
__global__ __launch_bounds__(1024) void finalize_kernel(
    const int* __restrict__ targets, float* __restrict__ ws,
    float* __restrict__ out) {
  const int wv = threadIdx.x >> 6, lane = threadIdx.x & 63;
  float a0 = 0.f, a1 = 0.f, a2 = 0.f, a3 = 0.f, a4 = 0.f;
#pragma unroll
  for (int it = 0; it < 2; ++it) {
    int i = threadIdx.x + it * 1024;
    if (i < NPART) {
      float v = ws[OFF_P + i];
      if (i < 313)       a0 += v;
      else if (i < 626)  a1 += v;
      else if (i < 939)  a2 += v;
      else if (i < 1564) a3 += v;
      else               a4 += v;
    }
  }
  a0 = wave_sum(a0); a1 = wave_sum(a1); a2 = wave_sum(a2);
  a3 = wave_sum(a3); a4 = wave_sum(a4);
  __shared__ float r5[16][5];
  __shared__ float slse[5];
  if (lane == 0) { r5[wv][0] = a0; r5[wv][1] = a1; r5[wv][2] = a2; r5[wv][3] = a3; r5[wv][4] = a4; }
  __syncthreads();
  if (threadIdx.x < 5) {
    float s = 0.f;
#pragma unroll
    for (int w = 0; w < 16; ++w) s += r5[w][threadIdx.x];
    slse[threadIdx.x] = logf(s);
  }
  __syncthreads();
  const float lse0 = slse[0], lse1 = slse[1], lse2 = slse[2], lse3 = slse[3], lse4 = slse[4];
  const float g0 = ws[10000] - lse0, g1 = ws[10001] - lse0;
  const float g2 = ws[10002] - lse0, g3 = ws[10003] - lse0;
  float s = 0.f;
#pragma unroll
  for (int it = 0; it < 4; ++it) {
    int t = targets[threadIdx.x + it * 1024];
    float lp;
    if (t < 10000)      lp = ws[OFF_HEAD + t] - lse0;
    else if (t < 20000) lp = ws[OFF_C0 + t - 10000] - lse1 + g0;
    else if (t < 40000) lp = ws[OFF_C1 + t - 20000] - lse2 + g1;
    else if (t < 80000) lp = ws[OFF_C2 + t - 40000] - lse3 + g2;
    else                lp = ws[OFF_C3 + t - 80000] - lse4 + g3;
    s += lp;
  }
  s = wave_sum(s);
  if (lane == 0) r5[wv][0] = s;
  __syncthreads();
  if (threadIdx.x == 0) {
    float tot = 0.f;
#pragma unroll
    for (int w = 0; w < 16; ++w) tot += r5[w][0];
    out[0] = -tot * (1.f / 4096.f);
  }
}

extern "C" void kernel_launch(void* const* d_in, const int* in_sizes, int n_in,
                              void* d_out, int out_size, void* d_ws, size_t ws_size,
                              hipStream_t stream) {
  const float* feat    = (const float*)d_in[0];
  const int*   targets = (const int*)d_in[1];
  const float* head_w  = (const float*)d_in[2];
  const float* t0p = (const float*)d_in[3];
  const float* t0w = (const float*)d_in[4];
  const float* t1p = (const float*)d_in[5];
  const float* t1w = (const float*)d_in[6];
  const float* t2p = (const float*)d_in[7];
  const float* t2w = (const float*)d_in[8];
  const float* t3p = (const float*)d_in[9];
  const float* t3w = (const float*)d_in[10];
  float* ws  = (float*)d_ws;
  float* out = (float*)d_out;

  proj_kernel<<<60, 256, 0, stream>>>(feat, t0p, t1p, t2p, t3p, ws);
  main_kernel<<<1877, 256, 0, stream>>>(feat, head_w, t0w, t1w, t2w, t3w, ws);
  finalize_kernel<<<1, 1024, 0, stream>>>(targets, ws, out);
}